// Round 1
// baseline (84.668 us; speedup 1.0000x reference)
//
#include <hip/hip_runtime.h>

// GIB layer: B=2, N=65536, M=8192, K=32; 16 each of cy/cone/disk/ellip gibs;
// out = mean_k(gib_vals) @ lambdas -> (B, M, 16). fp32 in / fp32 out.
//
// R6 post-mortem: wave = 2 queries x 32 lanes, broadcast gather in hot loop,
// ~40us kernel at VALUBusy 22% -> latency-bound on sidx->points dependent
// chain; 64-VGPR cap (8 waves/SIMD) forbids deep prefetch.
// R7: split gather out of the hot loop.
//   Phase A: one (q,k) pair per thread (256 = 8 queries x 32 k). Coalesced
//     sidx read -> one scattered point read -> rel coords + sqrt -> LDS
//     float4 (rx,ry,rz,s). Latency paid ONCE per block; all 2048 blocks
//     co-resident (8/CU), so ~1-2us grid-wide.
//   Phase B: hot loop reads ds_read_b128 broadcast (same addr per 32-lane
//     half = conflict-free), ~16 VALU + 2 exp2 per k. No global loads, no
//     sqrt in the loop. Should sit near the ~7-9us VALU/trans issue floor.
//   Epilogue (lambda matvec into bit-reversed slots + halving butterfly)
//   verified in R5/R6 - unchanged.

#define EPSF 1e-8f
#define LOG2E 1.4426950408889634f

constexpr int LAM_STRIDE = 18;  // floats; 18*dc % 32 == 0 only at dc=16 -> 2-way max (free)

__global__ __launch_bounds__(256, 8) void gib_kernel(
    const float* __restrict__ points,   // (B, 65536, 3)
    const float* __restrict__ qc,       // (B, 8192, 3)
    const int*   __restrict__ sidx,     // (B, 8192, 32)
    const float* __restrict__ cyp,      // (16,2)
    const float* __restrict__ conep,    // (16,2)
    const float* __restrict__ diskp,    // (16,2)
    const float* __restrict__ ellp,     // (16,3)
    const float* __restrict__ lam,      // (64,16)
    float*       __restrict__ out)      // (B, 8192, 16)
{
    __shared__ float  lamS[64 * LAM_STRIDE];   // 4.6 KB, scaled by 1/K
    __shared__ float4 relS[256];               // 4 KB: [local q 0..7][k 0..31] = (rx,ry,rz,s)

    const int tid = threadIdx.x;

    // ---- phase A: gather + rel precompute, one (q,k) per thread ----
    {
        const int ql = tid >> 5;               // local query 0..7
        const int kk = tid & 31;
        const int qg = blockIdx.x * 8 + ql;    // global query
        const int bb = qg >> 13;
        const int idx = sidx[qg * 32 + kk];    // coalesced dword
        const float* pp = points + ((size_t)(bb << 16) + (size_t)idx) * 3;
        const float* qq = qc + qg * 3;         // broadcast within 32-lane group
        float rx = pp[0] - qq[0];
        float ry = pp[1] - qq[1];
        float rz = pp[2] - qq[2];
        float r2 = rx * rx + ry * ry;
        float s  = __builtin_amdgcn_sqrtf(r2 + EPSF);
        relS[tid] = make_float4(rx, ry, rz, s);
    }

    // ---- stage lambda (64x16 -> stride-18 rows, scaled 1/32) ----
    {
        int g = tid >> 2, o = (tid & 3) * 4;
#pragma unroll
        for (int j = 0; j < 4; j++)
            lamS[g * LAM_STRIDE + o + j] = lam[g * 16 + o + j] * (1.0f / 32.0f);
    }

    const int l  = tid & 63;
    const int c  = l & 31;               // gib column: a0 = row c, a1 = row 32+c
    const int q  = blockIdx.x * 8 + (tid >> 5);   // wave half's global query

    // ---- per-lane branchless coefficients (before barrier: overlaps phase A) ----
    // a0 arg: u = al1*r2 + al2*s + al3*rz + al4 ; contrib = exp2(u*u*nb0)
    // a1 arg: v = rx2*A1 + ry2*B1 + rz2*C1     ; contrib = exp2(v)
    float al1, al2, al3, al4, nb0, A1, B1, C1;
    if (c < 16) {
        float c0 = cyp[2 * c], c1 = cyp[2 * c + 1];
        al1 = 1.f; al2 = 0.f; al3 = 0.f; al4 = -c0 * c0;
        nb0 = -LOG2E / (2.f * c1 * c1 + EPSF);
        float d0 = diskp[2 * c], d1 = diskp[2 * c + 1];
        float ai = -LOG2E / (d0 * d0 + EPSF);
        A1 = ai; B1 = ai; C1 = -LOG2E / (d1 * d1 + EPSF);
    } else {
        int cc = c - 16;
        float k0 = conep[2 * cc], k1 = conep[2 * cc + 1];
        al1 = 0.f; al2 = 1.f; al3 = -k0; al4 = 0.f;
        nb0 = -LOG2E / (2.f * k1 * k1 + EPSF);
        float e0 = ellp[3 * cc], e1 = ellp[3 * cc + 1], e2 = ellp[3 * cc + 2];
        A1 = -LOG2E / (e0 * e0 + EPSF);
        B1 = -LOG2E / (e1 * e1 + EPSF);
        C1 = -LOG2E / (e2 * e2 + EPSF);
    }

    __syncthreads();

    // ---- phase B: hot loop, LDS broadcast reads only ----
    const float4* rel = &relS[(tid >> 5) * 32];   // uniform across each 32-lane half

    float a0 = 0.f, a1 = 0.f;
#pragma unroll
    for (int k = 0; k < 32; k++) {
        float4 p = rel[k];                  // ds_read_b128, same addr per half = broadcast
        float rx2 = p.x * p.x, ry2 = p.y * p.y, rz2 = p.z * p.z;
        float r2 = rx2 + ry2;
        float u  = fmaf(al1, r2, fmaf(al2, p.w, fmaf(al3, p.z, al4)));
        a0 += __builtin_amdgcn_exp2f(u * u * nb0);
        float v  = fmaf(rx2, A1, fmaf(ry2, B1, rz2 * C1));
        a1 += __builtin_amdgcn_exp2f(v);
    }

    // ---- lambda matvec into bit-reversed slots (slot brev4(o) <- observer o) ----
    float sv[16];
    {
        const float* ra = &lamS[c * LAM_STRIDE];
        const float* rb = &lamS[(32 + c) * LAM_STRIDE];
        // brev4 table: o -> slot
        // 0->0 1->8 2->4 3->12 4->2 5->10 6->6 7->14 8->1 9->9 10->5 11->13 12->3 13->11 14->7 15->15
        { float2 La = *(const float2*)&ra[0];  float2 Lb = *(const float2*)&rb[0];
          sv[0]  = fmaf(a0, La.x, a1 * Lb.x); sv[8]  = fmaf(a0, La.y, a1 * Lb.y); }
        { float2 La = *(const float2*)&ra[2];  float2 Lb = *(const float2*)&rb[2];
          sv[4]  = fmaf(a0, La.x, a1 * Lb.x); sv[12] = fmaf(a0, La.y, a1 * Lb.y); }
        { float2 La = *(const float2*)&ra[4];  float2 Lb = *(const float2*)&rb[4];
          sv[2]  = fmaf(a0, La.x, a1 * Lb.x); sv[10] = fmaf(a0, La.y, a1 * Lb.y); }
        { float2 La = *(const float2*)&ra[6];  float2 Lb = *(const float2*)&rb[6];
          sv[6]  = fmaf(a0, La.x, a1 * Lb.x); sv[14] = fmaf(a0, La.y, a1 * Lb.y); }
        { float2 La = *(const float2*)&ra[8];  float2 Lb = *(const float2*)&rb[8];
          sv[1]  = fmaf(a0, La.x, a1 * Lb.x); sv[9]  = fmaf(a0, La.y, a1 * Lb.y); }
        { float2 La = *(const float2*)&ra[10]; float2 Lb = *(const float2*)&rb[10];
          sv[5]  = fmaf(a0, La.x, a1 * Lb.x); sv[13] = fmaf(a0, La.y, a1 * Lb.y); }
        { float2 La = *(const float2*)&ra[12]; float2 Lb = *(const float2*)&rb[12];
          sv[3]  = fmaf(a0, La.x, a1 * Lb.x); sv[11] = fmaf(a0, La.y, a1 * Lb.y); }
        { float2 La = *(const float2*)&ra[14]; float2 Lb = *(const float2*)&rb[14];
          sv[7]  = fmaf(a0, La.x, a1 * Lb.x); sv[15] = fmaf(a0, La.y, a1 * Lb.y); }
    }

    // ---- recursive-halving butterfly over the 32 lanes of this query ----
    {
        bool up = (c & 1);
#pragma unroll
        for (int i = 0; i < 8; i++) {
            float keep = up ? sv[i + 8] : sv[i];
            float send = up ? sv[i] : sv[i + 8];
            sv[i] = keep + __shfl_xor(send, 1, 64);
        }
    }
    {
        bool up = (c & 2);
#pragma unroll
        for (int i = 0; i < 4; i++) {
            float keep = up ? sv[i + 4] : sv[i];
            float send = up ? sv[i] : sv[i + 4];
            sv[i] = keep + __shfl_xor(send, 2, 64);
        }
    }
    {
        bool up = (c & 4);
#pragma unroll
        for (int i = 0; i < 2; i++) {
            float keep = up ? sv[i + 2] : sv[i];
            float send = up ? sv[i] : sv[i + 2];
            sv[i] = keep + __shfl_xor(send, 4, 64);
        }
    }
    {
        bool up = (c & 8);
        float keep = up ? sv[1] : sv[0];
        float send = up ? sv[0] : sv[1];
        sv[0] = keep + __shfl_xor(send, 8, 64);
    }
    // merge the two 16-lane halves (c vs c+16): both hold observer (c&15) partials
    sv[0] += __shfl_xor(sv[0], 16, 64);

    if (c < 16)
        out[q * 16 + c] = sv[0];
}

extern "C" void kernel_launch(void* const* d_in, const int* in_sizes, int n_in,
                              void* d_out, int out_size, void* d_ws, size_t ws_size,
                              hipStream_t stream) {
    const float* points = (const float*)d_in[0];
    const float* qc     = (const float*)d_in[1];
    const int*   sidx   = (const int*)d_in[2];
    // d_in[3] = mc_points: unused by the reference
    const float* cyp    = (const float*)d_in[4];
    const float* conep  = (const float*)d_in[5];
    const float* diskp  = (const float*)d_in[6];
    const float* ellp   = (const float*)d_in[7];
    const float* lam    = (const float*)d_in[8];
    float*       out    = (float*)d_out;

    const int totalQ = 2 * 8192;            // B*M = 16384, 8 queries/block
    dim3 grid(totalQ / 8), block(256);      // 2048 blocks = 8/CU = 32 waves/CU
    hipLaunchKernelGGL(gib_kernel, grid, block, 0, stream,
                       points, qc, sidx, cyp, conep, diskp, ellp, lam, out);
}